// Round 3
// baseline (921.406 us; speedup 1.0000x reference)
//
#include <hip/hip_runtime.h>

#define N_NODES 50000
#define N_EDGES 600000
#define N_GRAPHS 2048
#define EMB 128
#define TDIM 384                 // 3 * EMB, stacked message dim
#define HN (N_NODES * EMB)
#define SCAN_NB ((N_NODES + 255) / 256)   // 196

// ---------------- Atom encoder ----------------
__global__ __launch_bounds__(128) void k_atom(const int* __restrict__ x,
                                              const float* __restrict__ atom_emb,
                                              float* __restrict__ h) {
  int n = blockIdx.x, e = threadIdx.x;
  const int* xr = x + n * 9;
  float acc = 0.f;
#pragma unroll
  for (int c = 0; c < 9; ++c) acc += atom_emb[(c * 100 + xr[c]) * EMB + e];
  h[n * EMB + e] = acc;
}

// ---------------- CSR build: hist, 3-pass scan, scatter ----------------
__global__ __launch_bounds__(256) void k_hist(const int* __restrict__ ei, int* __restrict__ deg) {
  int e = blockIdx.x * 256 + threadIdx.x;
  if (e < N_EDGES) atomicAdd(&deg[ei[N_EDGES + e]], 1);
}

// Pass A: per-block exclusive scan; row_start gets block-local exclusive, partials gets block sum.
__global__ __launch_bounds__(256) void k_scan_a(const int* __restrict__ deg,
                                                int* __restrict__ row_start,
                                                int* __restrict__ partials) {
  __shared__ int s[256];
  const int tid = threadIdx.x;
  const int i = blockIdx.x * 256 + tid;
  int v = (i < N_NODES) ? deg[i] : 0;
  s[tid] = v;
  __syncthreads();
  for (int off = 1; off < 256; off <<= 1) {
    int t = (tid >= off) ? s[tid - off] : 0;
    __syncthreads();
    s[tid] += t;
    __syncthreads();
  }
  if (i < N_NODES) row_start[i] = s[tid] - v;
  if (tid == 255) partials[blockIdx.x] = s[255];
}

// Pass B: single block scans partials[SCAN_NB] exclusively; writes total to row_start[N].
__global__ __launch_bounds__(256) void k_scan_b(int* __restrict__ partials,
                                                int* __restrict__ row_start) {
  __shared__ int s[256];
  const int tid = threadIdx.x;
  int v = (tid < SCAN_NB) ? partials[tid] : 0;
  s[tid] = v;
  __syncthreads();
  for (int off = 1; off < 256; off <<= 1) {
    int t = (tid >= off) ? s[tid - off] : 0;
    __syncthreads();
    s[tid] += t;
    __syncthreads();
  }
  if (tid < SCAN_NB) partials[tid] = s[tid] - v;
  if (tid == 255) row_start[N_NODES] = s[255];
}

// Pass C: add block offsets; fill cursor.
__global__ __launch_bounds__(256) void k_scan_c(int* __restrict__ row_start,
                                                const int* __restrict__ partials,
                                                int* __restrict__ cursor) {
  const int i = blockIdx.x * 256 + threadIdx.x;
  if (i < N_NODES) {
    int r = row_start[i] + partials[blockIdx.x];
    row_start[i] = r;
    cursor[i] = r;
  }
}

// Scatter edges into CSR order; pre-expand the 3-layer edge weights (float4 each).
__global__ __launch_bounds__(256) void k_scatter(const int* __restrict__ ei,
                                                 const int* __restrict__ ea,
                                                 const float* __restrict__ bond_emb,  // [3][3][8][3]
                                                 int* __restrict__ cursor,
                                                 int* __restrict__ sorted_src,
                                                 float4* __restrict__ sew) {          // [3][E]
  int e = blockIdx.x * 256 + threadIdx.x;
  if (e >= N_EDGES) return;
  int src = ei[e], dst = ei[N_EDGES + e];
  int pos = atomicAdd(&cursor[dst], 1);
  sorted_src[pos] = src;
  int a0 = ea[e * 3 + 0], a1 = ea[e * 3 + 1], a2 = ea[e * 3 + 2];
#pragma unroll
  for (int layer = 0; layer < 3; ++layer) {
    const float* bl = bond_emb + layer * 72;
    float4 w;
    w.x = bl[a0 * 3 + 0] + bl[24 + a1 * 3 + 0] + bl[48 + a2 * 3 + 0];
    w.y = bl[a0 * 3 + 1] + bl[24 + a1 * 3 + 1] + bl[48 + a2 * 3 + 1];
    w.z = bl[a0 * 3 + 2] + bl[24 + a1 * 3 + 2] + bl[48 + a2 * 3 + 2];
    w.w = 0.f;
    sew[(size_t)layer * N_EDGES + pos] = w;
  }
}

// ---------------- Fused layer: aggregate tile into LDS, then GEMM+bias+relu+residual ----------------
// 32 nodes/block, 256 threads (4 waves). Phase 1: wave wv handles nodes wv*8..wv*8+7,
// lane covers 2 columns; t-row (384 floats) accumulated in regs, written to LDS.
// Phase 2: classic 4x4 register-tile GEMM over ts[32][384] x Wl[384][128].
__global__ __launch_bounds__(256) void k_layer(const int* __restrict__ sorted_src,
                                               const float4* __restrict__ sew_l,  // [E]
                                               const int* __restrict__ row_start,
                                               const float* __restrict__ h_in,
                                               const float* __restrict__ Wl,  // [384][128]
                                               const float* __restrict__ bl,  // [3][128]
                                               float* __restrict__ h_out,
                                               int do_relu) {
  __shared__ float ts[32 * TDIM];  // 48 KB
  const int nb = blockIdx.x * 32;
  const int wv = threadIdx.x >> 6;
  const int lane = threadIdx.x & 63;

  for (int i = 0; i < 8; ++i) {
    const int nl = wv * 8 + i;
    const int node = nb + nl;
    float2 a0 = {0.f, 0.f}, a1 = {0.f, 0.f}, a2 = {0.f, 0.f};
    if (node < N_NODES) {
      const int beg = row_start[node], end = row_start[node + 1];
      for (int e = beg; e < end; ++e) {
        int src = sorted_src[e];
        float4 w = sew_l[e];
        float2 hv = *(const float2*)(h_in + (size_t)src * EMB + lane * 2);
        a0.x += w.x * hv.x; a0.y += w.x * hv.y;
        a1.x += w.y * hv.x; a1.y += w.y * hv.y;
        a2.x += w.z * hv.x; a2.y += w.z * hv.y;
      }
    }
    float* tr = ts + nl * TDIM + lane * 2;
    *(float2*)(tr)       = a0;
    *(float2*)(tr + 128) = a1;
    *(float2*)(tr + 256) = a2;
  }
  __syncthreads();

  const int tx = threadIdx.x & 31;   // cols tx*4..+3
  const int ty = threadIdx.x >> 5;   // rows ty*4..+3
  float4 acc[4];
#pragma unroll
  for (int r = 0; r < 4; ++r) acc[r] = float4{0.f, 0.f, 0.f, 0.f};
  const float* wc = Wl + tx * 4;
  for (int j = 0; j < TDIM; j += 4) {
    float4 w0 = *(const float4*)(wc + (j + 0) * EMB);
    float4 w1 = *(const float4*)(wc + (j + 1) * EMB);
    float4 w2 = *(const float4*)(wc + (j + 2) * EMB);
    float4 w3 = *(const float4*)(wc + (j + 3) * EMB);
#pragma unroll
    for (int r = 0; r < 4; ++r) {
      float4 hv = *(const float4*)(ts + (ty * 4 + r) * TDIM + j);
      acc[r].x += hv.x * w0.x + hv.y * w1.x + hv.z * w2.x + hv.w * w3.x;
      acc[r].y += hv.x * w0.y + hv.y * w1.y + hv.z * w2.y + hv.w * w3.y;
      acc[r].z += hv.x * w0.z + hv.y * w1.z + hv.z * w2.z + hv.w * w3.z;
      acc[r].w += hv.x * w0.w + hv.y * w1.w + hv.z * w2.w + hv.w * w3.w;
    }
  }
  float4 b0 = *(const float4*)(bl + tx * 4);
  float4 b1 = *(const float4*)(bl + 128 + tx * 4);
  float4 b2 = *(const float4*)(bl + 256 + tx * 4);
  float4 bias = {b0.x + b1.x + b2.x, b0.y + b1.y + b2.y,
                 b0.z + b1.z + b2.z, b0.w + b1.w + b2.w};
#pragma unroll
  for (int r = 0; r < 4; ++r) {
    int n = nb + ty * 4 + r;
    if (n < N_NODES) {
      const float4* hip_ = (const float4*)(h_in + (size_t)n * EMB + tx * 4);
      float4* hop = (float4*)(h_out + (size_t)n * EMB + tx * 4);
      float4 hv = *hip_;
      float4 v = {acc[r].x + bias.x, acc[r].y + bias.y,
                  acc[r].z + bias.z, acc[r].w + bias.w};
      if (do_relu) {
        v.x = fmaxf(v.x, 0.f); v.y = fmaxf(v.y, 0.f);
        v.z = fmaxf(v.z, 0.f); v.w = fmaxf(v.w, 0.f);
      }
      *hop = float4{hv.x + v.x, hv.y + v.y, hv.z + v.z, hv.w + v.w};
    }
  }
}

// ---------------- mean-pool: run-length segmented (batch is sorted) ----------------
__global__ __launch_bounds__(128) void k_pool(const float* __restrict__ h,
                                              const int* __restrict__ batch,
                                              float* __restrict__ sums,
                                              float* __restrict__ counts) {
  const int e = threadIdx.x;
  const int n0 = blockIdx.x * 32;
  int g_cur = -1, run = 0;
  float acc = 0.f;
  for (int i = 0; i < 32; ++i) {
    int n = n0 + i;
    if (n >= N_NODES) break;
    int g = batch[n];
    if (g != g_cur) {
      if (g_cur >= 0) {
        atomicAdd(&sums[g_cur * EMB + e], acc);
        if (e == 0) atomicAdd(&counts[g_cur], (float)run);
      }
      g_cur = g; acc = 0.f; run = 0;
    }
    acc += h[(size_t)n * EMB + e];
    ++run;
  }
  if (g_cur >= 0) {
    atomicAdd(&sums[g_cur * EMB + e], acc);
    if (e == 0) atomicAdd(&counts[g_cur], (float)run);
  }
}

// ---------------- head ----------------
__global__ __launch_bounds__(128) void k_head(const float* __restrict__ sums,
                                              const float* __restrict__ counts,
                                              const float* __restrict__ fc1_w,
                                              const float* __restrict__ fc1_b,
                                              const float* __restrict__ fc2_w,
                                              const float* __restrict__ fc2_b,
                                              float* __restrict__ out) {
  __shared__ float hg[EMB];
  __shared__ float red[EMB];
  int g = blockIdx.x, e = threadIdx.x;
  float cnt = fmaxf(counts[g], 1.f);
  hg[e] = sums[g * EMB + e] / cnt;
  __syncthreads();
  float acc = fc1_b[e];
  for (int j = 0; j < EMB; ++j) acc += hg[j] * fc1_w[j * EMB + e];
  red[e] = acc * fc2_w[e];
  __syncthreads();
  for (int s = 64; s > 0; s >>= 1) {
    if (e < s) red[e] += red[e + s];
    __syncthreads();
  }
  if (e == 0) out[g] = red[0] + fc2_b[0];
}

extern "C" void kernel_launch(void* const* d_in, const int* in_sizes, int n_in,
                              void* d_out, int out_size, void* d_ws, size_t ws_size,
                              hipStream_t stream) {
  const int*   x        = (const int*)d_in[0];
  const int*   ei       = (const int*)d_in[1];
  const int*   ea       = (const int*)d_in[2];
  const int*   batch    = (const int*)d_in[3];
  const float* atom_emb = (const float*)d_in[4];
  const float* bond_emb = (const float*)d_in[5];
  const float* W        = (const float*)d_in[6];
  const float* b        = (const float*)d_in[7];
  const float* fc1_w    = (const float*)d_in[8];
  const float* fc1_b    = (const float*)d_in[9];
  const float* fc2_w    = (const float*)d_in[10];
  const float* fc2_b    = (const float*)d_in[11];
  float* out = (float*)d_out;

  float* ws = (float*)d_ws;
  float* h0        = ws;                          // HN
  float* h1        = h0 + HN;                     // HN
  float* sums      = h1 + HN;                     // N_GRAPHS*EMB
  float* counts    = sums + N_GRAPHS * EMB;       // N_GRAPHS
  int*   deg       = (int*)(counts + N_GRAPHS);   // N_NODES
  int*   row_start = deg + N_NODES;               // N_NODES+1
  int*   cursor    = row_start + N_NODES + 1;     // N_NODES
  int*   partials  = cursor + N_NODES;            // 256
  int*   sorted_src= partials + 256;              // N_EDGES
  // align sew to 16 bytes
  size_t off = (size_t)(sorted_src + N_EDGES) - (size_t)d_ws;
  off = (off + 15) & ~(size_t)15;
  float4* sew = (float4*)((char*)d_ws + off);     // 3 * N_EDGES float4

  hipMemsetAsync(deg, 0, N_NODES * sizeof(int), stream);
  k_atom<<<N_NODES, 128, 0, stream>>>(x, atom_emb, h0);
  k_hist<<<(N_EDGES + 255) / 256, 256, 0, stream>>>(ei, deg);
  k_scan_a<<<SCAN_NB, 256, 0, stream>>>(deg, row_start, partials);
  k_scan_b<<<1, 256, 0, stream>>>(partials, row_start);
  k_scan_c<<<SCAN_NB, 256, 0, stream>>>(row_start, partials, cursor);
  k_scatter<<<(N_EDGES + 255) / 256, 256, 0, stream>>>(ei, ea, bond_emb, cursor,
                                                       sorted_src, sew);

  const int nlb = (N_NODES + 31) / 32;
  float* hi = h0; float* ho = h1;
  for (int layer = 0; layer < 3; ++layer) {
    k_layer<<<nlb, 256, 0, stream>>>(sorted_src, sew + (size_t)layer * N_EDGES,
                                     row_start, hi, W + (size_t)layer * 3 * EMB * EMB,
                                     b + layer * 3 * EMB, ho, layer < 2 ? 1 : 0);
    float* tmp = hi; hi = ho; ho = tmp;
  }
  // final h is in `hi` after the swap (h1 after 3 layers)

  hipMemsetAsync(sums, 0, (N_GRAPHS * EMB + N_GRAPHS) * sizeof(float), stream);
  k_pool<<<(N_NODES + 31) / 32, 128, 0, stream>>>(hi, batch, sums, counts);
  k_head<<<N_GRAPHS, 128, 0, stream>>>(sums, counts, fc1_w, fc1_b, fc2_w, fc2_b, out);
}

// Round 4
// 657.629 us; speedup vs baseline: 1.4011x; 1.4011x over previous
//
#include <hip/hip_runtime.h>

#define N_NODES 50000
#define N_EDGES 600000
#define N_GRAPHS 2048
#define EMB 128
#define TDIM 384
#define HN (N_NODES * EMB)
#define SCAN_NB ((N_NODES + 255) / 256)   // 196

// ---------------- Atom encoder ----------------
__global__ __launch_bounds__(128) void k_atom(const int* __restrict__ x,
                                              const float* __restrict__ atom_emb,
                                              float* __restrict__ h) {
  int n = blockIdx.x, e = threadIdx.x;
  const int* xr = x + n * 9;
  float acc = 0.f;
#pragma unroll
  for (int c = 0; c < 9; ++c) acc += atom_emb[(c * 100 + xr[c]) * EMB + e];
  h[n * EMB + e] = acc;
}

// ---------------- CSR build ----------------
__global__ __launch_bounds__(256) void k_hist(const int* __restrict__ ei, int* __restrict__ deg) {
  int e = blockIdx.x * 256 + threadIdx.x;
  if (e < N_EDGES) atomicAdd(&deg[ei[N_EDGES + e]], 1);
}

__global__ __launch_bounds__(256) void k_scan_a(const int* __restrict__ deg,
                                                int* __restrict__ row_start,
                                                int* __restrict__ partials) {
  __shared__ int s[256];
  const int tid = threadIdx.x;
  const int i = blockIdx.x * 256 + tid;
  int v = (i < N_NODES) ? deg[i] : 0;
  s[tid] = v;
  __syncthreads();
  for (int off = 1; off < 256; off <<= 1) {
    int t = (tid >= off) ? s[tid - off] : 0;
    __syncthreads();
    s[tid] += t;
    __syncthreads();
  }
  if (i < N_NODES) row_start[i] = s[tid] - v;
  if (tid == 255) partials[blockIdx.x] = s[255];
}

__global__ __launch_bounds__(256) void k_scan_b(int* __restrict__ partials,
                                                int* __restrict__ row_start) {
  __shared__ int s[256];
  const int tid = threadIdx.x;
  int v = (tid < SCAN_NB) ? partials[tid] : 0;
  s[tid] = v;
  __syncthreads();
  for (int off = 1; off < 256; off <<= 1) {
    int t = (tid >= off) ? s[tid - off] : 0;
    __syncthreads();
    s[tid] += t;
    __syncthreads();
  }
  if (tid < SCAN_NB) partials[tid] = s[tid] - v;
  if (tid == 255) row_start[N_NODES] = s[255];
}

__global__ __launch_bounds__(256) void k_scan_c(int* __restrict__ row_start,
                                                const int* __restrict__ partials,
                                                int* __restrict__ cursor) {
  const int i = blockIdx.x * 256 + threadIdx.x;
  if (i < N_NODES) {
    int r = row_start[i] + partials[blockIdx.x];
    row_start[i] = r;
    cursor[i] = r;
  }
}

__global__ __launch_bounds__(256) void k_scatter(const int* __restrict__ ei,
                                                 const int* __restrict__ ea,
                                                 const float* __restrict__ bond_emb,  // [3][3][8][3]
                                                 int* __restrict__ cursor,
                                                 int* __restrict__ sorted_src,
                                                 float4* __restrict__ sew) {          // [3][E]
  int e = blockIdx.x * 256 + threadIdx.x;
  if (e >= N_EDGES) return;
  int src = ei[e], dst = ei[N_EDGES + e];
  int pos = atomicAdd(&cursor[dst], 1);
  sorted_src[pos] = src;
  int a0 = ea[e * 3 + 0], a1 = ea[e * 3 + 1], a2 = ea[e * 3 + 2];
#pragma unroll
  for (int layer = 0; layer < 3; ++layer) {
    const float* bl = bond_emb + layer * 72;
    float4 w;
    w.x = bl[a0 * 3 + 0] + bl[24 + a1 * 3 + 0] + bl[48 + a2 * 3 + 0];
    w.y = bl[a0 * 3 + 1] + bl[24 + a1 * 3 + 1] + bl[48 + a2 * 3 + 1];
    w.z = bl[a0 * 3 + 2] + bl[24 + a1 * 3 + 2] + bl[48 + a2 * 3 + 2];
    w.w = 0.f;
    sew[(size_t)layer * N_EDGES + pos] = w;
  }
}

// ---------------- Edge aggregation: one wave per node, unroll x4 for MLP ----------------
__global__ __launch_bounds__(256) void k_agg(const int* __restrict__ sorted_src,
                                             const float4* __restrict__ sew_l,
                                             const int* __restrict__ row_start,
                                             const float* __restrict__ h,
                                             float* __restrict__ t) {
  const int node = blockIdx.x * 4 + (threadIdx.x >> 6);
  const int lane = threadIdx.x & 63;
  const int beg = row_start[node], end = row_start[node + 1];
  float2 a0 = {0.f, 0.f}, a1 = {0.f, 0.f}, a2 = {0.f, 0.f};
  int e = beg;
  for (; e + 4 <= end; e += 4) {
    int s0 = sorted_src[e],     s1 = sorted_src[e + 1];
    int s2 = sorted_src[e + 2], s3 = sorted_src[e + 3];
    float4 w0 = sew_l[e],     w1 = sew_l[e + 1];
    float4 w2 = sew_l[e + 2], w3 = sew_l[e + 3];
    float2 v0 = *(const float2*)(h + (size_t)s0 * EMB + lane * 2);
    float2 v1 = *(const float2*)(h + (size_t)s1 * EMB + lane * 2);
    float2 v2 = *(const float2*)(h + (size_t)s2 * EMB + lane * 2);
    float2 v3 = *(const float2*)(h + (size_t)s3 * EMB + lane * 2);
    a0.x += w0.x * v0.x + w1.x * v1.x + w2.x * v2.x + w3.x * v3.x;
    a0.y += w0.x * v0.y + w1.x * v1.y + w2.x * v2.y + w3.x * v3.y;
    a1.x += w0.y * v0.x + w1.y * v1.x + w2.y * v2.x + w3.y * v3.x;
    a1.y += w0.y * v0.y + w1.y * v1.y + w2.y * v2.y + w3.y * v3.y;
    a2.x += w0.z * v0.x + w1.z * v1.x + w2.z * v2.x + w3.z * v3.x;
    a2.y += w0.z * v0.y + w1.z * v1.y + w2.z * v2.y + w3.z * v3.y;
  }
  for (; e < end; ++e) {
    int s = sorted_src[e];
    float4 w = sew_l[e];
    float2 v = *(const float2*)(h + (size_t)s * EMB + lane * 2);
    a0.x += w.x * v.x; a0.y += w.x * v.y;
    a1.x += w.y * v.x; a1.y += w.y * v.y;
    a2.x += w.z * v.x; a2.y += w.z * v.y;
  }
  float* tr = t + (size_t)node * TDIM + lane * 2;
  *(float2*)(tr)       = a0;
  *(float2*)(tr + 128) = a1;
  *(float2*)(tr + 256) = a2;
}

// ---------------- GEMM + bias + relu + residual (h updated in place) ----------------
__global__ __launch_bounds__(256) void k_gemm_fused(const float* __restrict__ t,
                                                    const float* __restrict__ Wl,  // [384][128]
                                                    const float* __restrict__ bl,  // [3][128]
                                                    float* __restrict__ h,
                                                    int do_relu) {
  __shared__ float ts[32 * TDIM];  // 48 KB
  const int nb = blockIdx.x * 32;
  const float4* tg = (const float4*)(t + (size_t)nb * TDIM);
  float4* tsv = (float4*)ts;
  for (int i = threadIdx.x; i < 32 * TDIM / 4; i += 256) {
    int row = i / (TDIM / 4);
    tsv[i] = (nb + row < N_NODES) ? tg[i] : float4{0.f, 0.f, 0.f, 0.f};
  }
  __syncthreads();
  const int tx = threadIdx.x & 31;
  const int ty = threadIdx.x >> 5;
  float4 acc[4];
#pragma unroll
  for (int r = 0; r < 4; ++r) acc[r] = float4{0.f, 0.f, 0.f, 0.f};
  const float* wc = Wl + tx * 4;
  for (int j = 0; j < TDIM; j += 4) {
    float4 w0 = *(const float4*)(wc + (j + 0) * EMB);
    float4 w1 = *(const float4*)(wc + (j + 1) * EMB);
    float4 w2 = *(const float4*)(wc + (j + 2) * EMB);
    float4 w3 = *(const float4*)(wc + (j + 3) * EMB);
#pragma unroll
    for (int r = 0; r < 4; ++r) {
      float4 hv = *(const float4*)(ts + (ty * 4 + r) * TDIM + j);
      acc[r].x += hv.x * w0.x + hv.y * w1.x + hv.z * w2.x + hv.w * w3.x;
      acc[r].y += hv.x * w0.y + hv.y * w1.y + hv.z * w2.y + hv.w * w3.y;
      acc[r].z += hv.x * w0.z + hv.y * w1.z + hv.z * w2.z + hv.w * w3.z;
      acc[r].w += hv.x * w0.w + hv.y * w1.w + hv.z * w2.w + hv.w * w3.w;
    }
  }
  float4 b0 = *(const float4*)(bl + tx * 4);
  float4 b1 = *(const float4*)(bl + 128 + tx * 4);
  float4 b2 = *(const float4*)(bl + 256 + tx * 4);
  float4 bias = {b0.x + b1.x + b2.x, b0.y + b1.y + b2.y,
                 b0.z + b1.z + b2.z, b0.w + b1.w + b2.w};
#pragma unroll
  for (int r = 0; r < 4; ++r) {
    int n = nb + ty * 4 + r;
    if (n < N_NODES) {
      float4* hp = (float4*)(h + (size_t)n * EMB + tx * 4);
      float4 hv = *hp;
      float4 v = {acc[r].x + bias.x, acc[r].y + bias.y,
                  acc[r].z + bias.z, acc[r].w + bias.w};
      if (do_relu) {
        v.x = fmaxf(v.x, 0.f); v.y = fmaxf(v.y, 0.f);
        v.z = fmaxf(v.z, 0.f); v.w = fmaxf(v.w, 0.f);
      }
      *hp = float4{hv.x + v.x, hv.y + v.y, hv.z + v.z, hv.w + v.w};
    }
  }
}

// ---------------- mean-pool: run-length segmented ----------------
__global__ __launch_bounds__(128) void k_pool(const float* __restrict__ h,
                                              const int* __restrict__ batch,
                                              float* __restrict__ sums,
                                              float* __restrict__ counts) {
  const int e = threadIdx.x;
  const int n0 = blockIdx.x * 32;
  int g_cur = -1, run = 0;
  float acc = 0.f;
  for (int i = 0; i < 32; ++i) {
    int n = n0 + i;
    if (n >= N_NODES) break;
    int g = batch[n];
    if (g != g_cur) {
      if (g_cur >= 0) {
        atomicAdd(&sums[g_cur * EMB + e], acc);
        if (e == 0) atomicAdd(&counts[g_cur], (float)run);
      }
      g_cur = g; acc = 0.f; run = 0;
    }
    acc += h[(size_t)n * EMB + e];
    ++run;
  }
  if (g_cur >= 0) {
    atomicAdd(&sums[g_cur * EMB + e], acc);
    if (e == 0) atomicAdd(&counts[g_cur], (float)run);
  }
}

// ---------------- head ----------------
__global__ __launch_bounds__(128) void k_head(const float* __restrict__ sums,
                                              const float* __restrict__ counts,
                                              const float* __restrict__ fc1_w,
                                              const float* __restrict__ fc1_b,
                                              const float* __restrict__ fc2_w,
                                              const float* __restrict__ fc2_b,
                                              float* __restrict__ out) {
  __shared__ float hg[EMB];
  __shared__ float red[EMB];
  int g = blockIdx.x, e = threadIdx.x;
  float cnt = fmaxf(counts[g], 1.f);
  hg[e] = sums[g * EMB + e] / cnt;
  __syncthreads();
  float acc = fc1_b[e];
  for (int j = 0; j < EMB; ++j) acc += hg[j] * fc1_w[j * EMB + e];
  red[e] = acc * fc2_w[e];
  __syncthreads();
  for (int s = 64; s > 0; s >>= 1) {
    if (e < s) red[e] += red[e + s];
    __syncthreads();
  }
  if (e == 0) out[g] = red[0] + fc2_b[0];
}

extern "C" void kernel_launch(void* const* d_in, const int* in_sizes, int n_in,
                              void* d_out, int out_size, void* d_ws, size_t ws_size,
                              hipStream_t stream) {
  const int*   x        = (const int*)d_in[0];
  const int*   ei       = (const int*)d_in[1];
  const int*   ea       = (const int*)d_in[2];
  const int*   batch    = (const int*)d_in[3];
  const float* atom_emb = (const float*)d_in[4];
  const float* bond_emb = (const float*)d_in[5];
  const float* W        = (const float*)d_in[6];
  const float* b        = (const float*)d_in[7];
  const float* fc1_w    = (const float*)d_in[8];
  const float* fc1_b    = (const float*)d_in[9];
  const float* fc2_w    = (const float*)d_in[10];
  const float* fc2_b    = (const float*)d_in[11];
  float* out = (float*)d_out;

  float* ws = (float*)d_ws;
  float* h         = ws;                          // HN
  float* t         = h + HN;                      // N*384
  float* sums      = t + (size_t)N_NODES * TDIM;  // N_GRAPHS*EMB
  float* counts    = sums + N_GRAPHS * EMB;       // N_GRAPHS
  int*   deg       = (int*)(counts + N_GRAPHS);   // N_NODES
  int*   row_start = deg + N_NODES;               // N_NODES+1
  int*   cursor    = row_start + N_NODES + 1;     // N_NODES
  int*   partials  = cursor + N_NODES;            // 256
  int*   sorted_src= partials + 256;              // N_EDGES
  size_t off = (size_t)(sorted_src + N_EDGES) - (size_t)d_ws;
  off = (off + 15) & ~(size_t)15;
  float4* sew = (float4*)((char*)d_ws + off);     // 3 * N_EDGES

  hipMemsetAsync(deg, 0, N_NODES * sizeof(int), stream);
  k_atom<<<N_NODES, 128, 0, stream>>>(x, atom_emb, h);
  k_hist<<<(N_EDGES + 255) / 256, 256, 0, stream>>>(ei, deg);
  k_scan_a<<<SCAN_NB, 256, 0, stream>>>(deg, row_start, partials);
  k_scan_b<<<1, 256, 0, stream>>>(partials, row_start);
  k_scan_c<<<SCAN_NB, 256, 0, stream>>>(row_start, partials, cursor);
  k_scatter<<<(N_EDGES + 255) / 256, 256, 0, stream>>>(ei, ea, bond_emb, cursor,
                                                       sorted_src, sew);

  for (int layer = 0; layer < 3; ++layer) {
    k_agg<<<N_NODES / 4, 256, 0, stream>>>(sorted_src, sew + (size_t)layer * N_EDGES,
                                           row_start, h, t);
    k_gemm_fused<<<(N_NODES + 31) / 32, 256, 0, stream>>>(
        t, W + (size_t)layer * 3 * EMB * EMB, b + layer * 3 * EMB, h, layer < 2 ? 1 : 0);
  }

  hipMemsetAsync(sums, 0, (N_GRAPHS * EMB + N_GRAPHS) * sizeof(float), stream);
  k_pool<<<(N_NODES + 31) / 32, 128, 0, stream>>>(h, batch, sums, counts);
  k_head<<<N_GRAPHS, 128, 0, stream>>>(sums, counts, fc1_w, fc1_b, fc2_w, fc2_b, out);
}

// Round 5
// 577.648 us; speedup vs baseline: 1.5951x; 1.1385x over previous
//
#include <hip/hip_runtime.h>

#define N_NODES 50000
#define N_EDGES 600000
#define N_GRAPHS 2048
#define EMB 128
#define TDIM 384
#define HN (N_NODES * EMB)
#define SCAN_NB ((N_NODES + 255) / 256)   // 196

typedef __attribute__((ext_vector_type(8))) short bf16x8;
typedef __attribute__((ext_vector_type(4))) float f32x4;
#define MFMA_BF16(a, b, c) __builtin_amdgcn_mfma_f32_16x16x32_bf16(a, b, c, 0, 0, 0)

__device__ inline unsigned short f2bf(float f) {
  unsigned int u = __float_as_uint(f);
  u += 0x7fffu + ((u >> 16) & 1u);   // round to nearest even
  return (unsigned short)(u >> 16);
}
__device__ inline float bf2f(unsigned short b) {
  return __uint_as_float(((unsigned int)b) << 16);
}

// ---------------- Atom encoder ----------------
__global__ __launch_bounds__(128) void k_atom(const int* __restrict__ x,
                                              const float* __restrict__ atom_emb,
                                              float* __restrict__ h) {
  int n = blockIdx.x, e = threadIdx.x;
  const int* xr = x + n * 9;
  float acc = 0.f;
#pragma unroll
  for (int c = 0; c < 9; ++c) acc += atom_emb[(c * 100 + xr[c]) * EMB + e];
  h[n * EMB + e] = acc;
}

// ---------------- CSR build ----------------
__global__ __launch_bounds__(256) void k_hist(const int* __restrict__ ei, int* __restrict__ deg) {
  int e = blockIdx.x * 256 + threadIdx.x;
  if (e < N_EDGES) atomicAdd(&deg[ei[N_EDGES + e]], 1);
}

__global__ __launch_bounds__(256) void k_scan_a(const int* __restrict__ deg,
                                                int* __restrict__ row_start,
                                                int* __restrict__ partials) {
  __shared__ int s[256];
  const int tid = threadIdx.x;
  const int i = blockIdx.x * 256 + tid;
  int v = (i < N_NODES) ? deg[i] : 0;
  s[tid] = v;
  __syncthreads();
  for (int off = 1; off < 256; off <<= 1) {
    int t = (tid >= off) ? s[tid - off] : 0;
    __syncthreads();
    s[tid] += t;
    __syncthreads();
  }
  if (i < N_NODES) row_start[i] = s[tid] - v;
  if (tid == 255) partials[blockIdx.x] = s[255];
}

__global__ __launch_bounds__(256) void k_scan_b(int* __restrict__ partials,
                                                int* __restrict__ row_start) {
  __shared__ int s[256];
  const int tid = threadIdx.x;
  int v = (tid < SCAN_NB) ? partials[tid] : 0;
  s[tid] = v;
  __syncthreads();
  for (int off = 1; off < 256; off <<= 1) {
    int t = (tid >= off) ? s[tid - off] : 0;
    __syncthreads();
    s[tid] += t;
    __syncthreads();
  }
  if (tid < SCAN_NB) partials[tid] = s[tid] - v;
  if (tid == 255) row_start[N_NODES] = s[255];
}

__global__ __launch_bounds__(256) void k_scan_c(int* __restrict__ row_start,
                                                const int* __restrict__ partials,
                                                int* __restrict__ cursor) {
  const int i = blockIdx.x * 256 + threadIdx.x;
  if (i < N_NODES) {
    int r = row_start[i] + partials[blockIdx.x];
    row_start[i] = r;
    cursor[i] = r;
  }
}

__global__ __launch_bounds__(256) void k_scatter(const int* __restrict__ ei,
                                                 const int* __restrict__ ea,
                                                 const float* __restrict__ bond_emb,
                                                 int* __restrict__ cursor,
                                                 int* __restrict__ sorted_src,
                                                 float4* __restrict__ sew) {
  int e = blockIdx.x * 256 + threadIdx.x;
  if (e >= N_EDGES) return;
  int src = ei[e], dst = ei[N_EDGES + e];
  int pos = atomicAdd(&cursor[dst], 1);
  sorted_src[pos] = src;
  int a0 = ea[e * 3 + 0], a1 = ea[e * 3 + 1], a2 = ea[e * 3 + 2];
#pragma unroll
  for (int layer = 0; layer < 3; ++layer) {
    const float* bl = bond_emb + layer * 72;
    float4 w;
    w.x = bl[a0 * 3 + 0] + bl[24 + a1 * 3 + 0] + bl[48 + a2 * 3 + 0];
    w.y = bl[a0 * 3 + 1] + bl[24 + a1 * 3 + 1] + bl[48 + a2 * 3 + 1];
    w.z = bl[a0 * 3 + 2] + bl[24 + a1 * 3 + 2] + bl[48 + a2 * 3 + 2];
    w.w = 0.f;
    sew[(size_t)layer * N_EDGES + pos] = w;
  }
}

// ---------------- W -> W_T split bf16: wt[layer*128+c][k], k = conv*128 + j ----------------
__global__ __launch_bounds__(384) void k_wconv(const float* __restrict__ W,
                                               unsigned short* __restrict__ wt_hi,
                                               unsigned short* __restrict__ wt_lo) {
  int layer = blockIdx.x >> 7, c = blockIdx.x & 127, k = threadIdx.x;
  float v = W[(((layer * 3 + (k >> 7)) * 128) + (k & 127)) * 128 + c];
  unsigned short hi = f2bf(v);
  float rem = v - bf2f(hi);
  size_t idx = (size_t)blockIdx.x * 384 + k;
  wt_hi[idx] = hi;
  wt_lo[idx] = f2bf(rem);
}

// ---------------- Edge aggregation -> t_hi/t_lo (split bf16) ----------------
__device__ inline void store_split(unsigned short* th, unsigned short* tl,
                                   size_t idx, float2 v) {
  unsigned short hx = f2bf(v.x), hy = f2bf(v.y);
  *(ushort2*)(th + idx) = ushort2{hx, hy};
  *(ushort2*)(tl + idx) = ushort2{f2bf(v.x - bf2f(hx)), f2bf(v.y - bf2f(hy))};
}

__global__ __launch_bounds__(256) void k_agg(const int* __restrict__ sorted_src,
                                             const float4* __restrict__ sew_l,
                                             const int* __restrict__ row_start,
                                             const float* __restrict__ h,
                                             unsigned short* __restrict__ t_hi,
                                             unsigned short* __restrict__ t_lo) {
  const int node = blockIdx.x * 4 + (threadIdx.x >> 6);
  const int lane = threadIdx.x & 63;
  const int beg = row_start[node], end = row_start[node + 1];
  float2 a0 = {0.f, 0.f}, a1 = {0.f, 0.f}, a2 = {0.f, 0.f};
  int e = beg;
  for (; e + 4 <= end; e += 4) {
    int s0 = sorted_src[e],     s1 = sorted_src[e + 1];
    int s2 = sorted_src[e + 2], s3 = sorted_src[e + 3];
    float4 w0 = sew_l[e],     w1 = sew_l[e + 1];
    float4 w2 = sew_l[e + 2], w3 = sew_l[e + 3];
    float2 v0 = *(const float2*)(h + (size_t)s0 * EMB + lane * 2);
    float2 v1 = *(const float2*)(h + (size_t)s1 * EMB + lane * 2);
    float2 v2 = *(const float2*)(h + (size_t)s2 * EMB + lane * 2);
    float2 v3 = *(const float2*)(h + (size_t)s3 * EMB + lane * 2);
    a0.x += w0.x * v0.x + w1.x * v1.x + w2.x * v2.x + w3.x * v3.x;
    a0.y += w0.x * v0.y + w1.x * v1.y + w2.x * v2.y + w3.x * v3.y;
    a1.x += w0.y * v0.x + w1.y * v1.x + w2.y * v2.x + w3.y * v3.x;
    a1.y += w0.y * v0.y + w1.y * v1.y + w2.y * v2.y + w3.y * v3.y;
    a2.x += w0.z * v0.x + w1.z * v1.x + w2.z * v2.x + w3.z * v3.x;
    a2.y += w0.z * v0.y + w1.z * v1.y + w2.z * v2.y + w3.z * v3.y;
  }
  for (; e < end; ++e) {
    int s = sorted_src[e];
    float4 w = sew_l[e];
    float2 v = *(const float2*)(h + (size_t)s * EMB + lane * 2);
    a0.x += w.x * v.x; a0.y += w.x * v.y;
    a1.x += w.y * v.x; a1.y += w.y * v.y;
    a2.x += w.z * v.x; a2.y += w.z * v.y;
  }
  size_t base = (size_t)node * TDIM + lane * 2;
  store_split(t_hi, t_lo, base, a0);
  store_split(t_hi, t_lo, base + 128, a1);
  store_split(t_hi, t_lo, base + 256, a2);
}

// ---------------- MFMA GEMM + bias + relu + residual ----------------
// Block: 64 rows x 128 cols, 4 waves. Wave w: rows (w&1)*32 (2 tiles of 16),
// cols (w>>1)*64 (4 tiles of 16). K=384 in 12 steps of 32. bf16x3 split product.
// A-frag: A[m=lane&15][k=quad*8+j] -> 16B contiguous load from t row.
// B-frag: B[k][n=lane&15]          -> 16B contiguous load from W_T row.
// C/D:    col=lane&15, row=quad*4+reg.
__global__ __launch_bounds__(256) void k_mfma(const unsigned short* __restrict__ t_hi,
                                              const unsigned short* __restrict__ t_lo,
                                              const unsigned short* __restrict__ wt_hi,
                                              const unsigned short* __restrict__ wt_lo,
                                              const float* __restrict__ bl,  // [3][128]
                                              float* __restrict__ h,
                                              int do_relu) {
  const int wv = threadIdx.x >> 6;
  const int lane = threadIdx.x & 63;
  const int r_base = blockIdx.x * 64 + (wv & 1) * 32;
  const int c_base = (wv >> 1) * 64;
  const int m = lane & 15;
  const int kq = lane >> 4;       // quad 0..3

  int rowA0 = r_base + m;       if (rowA0 >= N_NODES) rowA0 = N_NODES - 1;
  int rowA1 = r_base + 16 + m;  if (rowA1 >= N_NODES) rowA1 = N_NODES - 1;
  const unsigned short* pA0h = t_hi + (size_t)rowA0 * TDIM + kq * 8;
  const unsigned short* pA1h = t_hi + (size_t)rowA1 * TDIM + kq * 8;
  const unsigned short* pA0l = t_lo + (size_t)rowA0 * TDIM + kq * 8;
  const unsigned short* pA1l = t_lo + (size_t)rowA1 * TDIM + kq * 8;

  const unsigned short* pBh[4];
  const unsigned short* pBl[4];
  float bias[4];
#pragma unroll
  for (int ct = 0; ct < 4; ++ct) {
    int c = c_base + ct * 16 + m;
    pBh[ct] = wt_hi + (size_t)c * TDIM + kq * 8;
    pBl[ct] = wt_lo + (size_t)c * TDIM + kq * 8;
    bias[ct] = bl[c] + bl[128 + c] + bl[256 + c];
  }

  f32x4 acc[2][4];
#pragma unroll
  for (int rt = 0; rt < 2; ++rt)
#pragma unroll
    for (int ct = 0; ct < 4; ++ct) acc[rt][ct] = f32x4{0.f, 0.f, 0.f, 0.f};

#pragma unroll
  for (int kc = 0; kc < 12; ++kc) {
    const int off = kc * 32;
    bf16x8 A0h = *(const bf16x8*)(pA0h + off);
    bf16x8 A1h = *(const bf16x8*)(pA1h + off);
    bf16x8 A0l = *(const bf16x8*)(pA0l + off);
    bf16x8 A1l = *(const bf16x8*)(pA1l + off);
#pragma unroll
    for (int ct = 0; ct < 4; ++ct) {
      bf16x8 Bh = *(const bf16x8*)(pBh[ct] + off);
      bf16x8 Bl = *(const bf16x8*)(pBl[ct] + off);
      acc[0][ct] = MFMA_BF16(A0h, Bh, acc[0][ct]);
      acc[0][ct] = MFMA_BF16(A0h, Bl, acc[0][ct]);
      acc[0][ct] = MFMA_BF16(A0l, Bh, acc[0][ct]);
      acc[1][ct] = MFMA_BF16(A1h, Bh, acc[1][ct]);
      acc[1][ct] = MFMA_BF16(A1h, Bl, acc[1][ct]);
      acc[1][ct] = MFMA_BF16(A1l, Bh, acc[1][ct]);
    }
  }

#pragma unroll
  for (int rt = 0; rt < 2; ++rt) {
#pragma unroll
    for (int r = 0; r < 4; ++r) {
      int row = r_base + rt * 16 + kq * 4 + r;
      if (row < N_NODES) {
#pragma unroll
        for (int ct = 0; ct < 4; ++ct) {
          int col = c_base + ct * 16 + m;
          size_t idx = (size_t)row * EMB + col;
          float v = acc[rt][ct][r] + bias[ct];
          if (do_relu) v = fmaxf(v, 0.f);
          h[idx] += v;
        }
      }
    }
  }
}

// ---------------- mean-pool: run-length segmented ----------------
__global__ __launch_bounds__(128) void k_pool(const float* __restrict__ h,
                                              const int* __restrict__ batch,
                                              float* __restrict__ sums,
                                              float* __restrict__ counts) {
  const int e = threadIdx.x;
  const int n0 = blockIdx.x * 32;
  int g_cur = -1, run = 0;
  float acc = 0.f;
  for (int i = 0; i < 32; ++i) {
    int n = n0 + i;
    if (n >= N_NODES) break;
    int g = batch[n];
    if (g != g_cur) {
      if (g_cur >= 0) {
        atomicAdd(&sums[g_cur * EMB + e], acc);
        if (e == 0) atomicAdd(&counts[g_cur], (float)run);
      }
      g_cur = g; acc = 0.f; run = 0;
    }
    acc += h[(size_t)n * EMB + e];
    ++run;
  }
  if (g_cur >= 0) {
    atomicAdd(&sums[g_cur * EMB + e], acc);
    if (e == 0) atomicAdd(&counts[g_cur], (float)run);
  }
}

// ---------------- head ----------------
__global__ __launch_bounds__(128) void k_head(const float* __restrict__ sums,
                                              const float* __restrict__ counts,
                                              const float* __restrict__ fc1_w,
                                              const float* __restrict__ fc1_b,
                                              const float* __restrict__ fc2_w,
                                              const float* __restrict__ fc2_b,
                                              float* __restrict__ out) {
  __shared__ float hg[EMB];
  __shared__ float red[EMB];
  int g = blockIdx.x, e = threadIdx.x;
  float cnt = fmaxf(counts[g], 1.f);
  hg[e] = sums[g * EMB + e] / cnt;
  __syncthreads();
  float acc = fc1_b[e];
  for (int j = 0; j < EMB; ++j) acc += hg[j] * fc1_w[j * EMB + e];
  red[e] = acc * fc2_w[e];
  __syncthreads();
  for (int s = 64; s > 0; s >>= 1) {
    if (e < s) red[e] += red[e + s];
    __syncthreads();
  }
  if (e == 0) out[g] = red[0] + fc2_b[0];
}

extern "C" void kernel_launch(void* const* d_in, const int* in_sizes, int n_in,
                              void* d_out, int out_size, void* d_ws, size_t ws_size,
                              hipStream_t stream) {
  const int*   x        = (const int*)d_in[0];
  const int*   ei       = (const int*)d_in[1];
  const int*   ea       = (const int*)d_in[2];
  const int*   batch    = (const int*)d_in[3];
  const float* atom_emb = (const float*)d_in[4];
  const float* bond_emb = (const float*)d_in[5];
  const float* W        = (const float*)d_in[6];
  const float* b        = (const float*)d_in[7];
  const float* fc1_w    = (const float*)d_in[8];
  const float* fc1_b    = (const float*)d_in[9];
  const float* fc2_w    = (const float*)d_in[10];
  const float* fc2_b    = (const float*)d_in[11];
  float* out = (float*)d_out;

  char* p = (char*)d_ws;
  auto alloc = [&](size_t bytes) { char* r = p; p += (bytes + 255) & ~(size_t)255; return r; };
  float*          h          = (float*)alloc((size_t)HN * 4);
  unsigned short* t_hi       = (unsigned short*)alloc((size_t)N_NODES * TDIM * 2);
  unsigned short* t_lo       = (unsigned short*)alloc((size_t)N_NODES * TDIM * 2);
  unsigned short* wt_hi      = (unsigned short*)alloc((size_t)3 * 128 * TDIM * 2);
  unsigned short* wt_lo      = (unsigned short*)alloc((size_t)3 * 128 * TDIM * 2);
  float*          sums       = (float*)alloc((size_t)N_GRAPHS * EMB * 4);
  float*          counts     = (float*)alloc((size_t)N_GRAPHS * 4);
  int*            deg        = (int*)alloc((size_t)N_NODES * 4);
  int*            row_start  = (int*)alloc((size_t)(N_NODES + 1) * 4);
  int*            cursor     = (int*)alloc((size_t)N_NODES * 4);
  int*            partials   = (int*)alloc(256 * 4);
  int*            sorted_src = (int*)alloc((size_t)N_EDGES * 4);
  float4*         sew        = (float4*)alloc((size_t)3 * N_EDGES * 16);

  hipMemsetAsync(deg, 0, N_NODES * sizeof(int), stream);
  k_atom<<<N_NODES, 128, 0, stream>>>(x, atom_emb, h);
  k_hist<<<(N_EDGES + 255) / 256, 256, 0, stream>>>(ei, deg);
  k_scan_a<<<SCAN_NB, 256, 0, stream>>>(deg, row_start, partials);
  k_scan_b<<<1, 256, 0, stream>>>(partials, row_start);
  k_scan_c<<<SCAN_NB, 256, 0, stream>>>(row_start, partials, cursor);
  k_scatter<<<(N_EDGES + 255) / 256, 256, 0, stream>>>(ei, ea, bond_emb, cursor,
                                                       sorted_src, sew);
  k_wconv<<<3 * 128, 384, 0, stream>>>(W, wt_hi, wt_lo);

  const int gemm_blocks = (N_NODES + 63) / 64;  // 782
  for (int layer = 0; layer < 3; ++layer) {
    k_agg<<<N_NODES / 4, 256, 0, stream>>>(sorted_src, sew + (size_t)layer * N_EDGES,
                                           row_start, h, t_hi, t_lo);
    k_mfma<<<gemm_blocks, 256, 0, stream>>>(
        t_hi, t_lo, wt_hi + (size_t)layer * 128 * TDIM, wt_lo + (size_t)layer * 128 * TDIM,
        b + layer * 3 * EMB, h, layer < 2 ? 1 : 0);
  }

  hipMemsetAsync(sums, 0, (N_GRAPHS * EMB + 256) * sizeof(float), stream);
  k_pool<<<(N_NODES + 31) / 32, 128, 0, stream>>>(h, batch, sums, counts);
  k_head<<<N_GRAPHS, 128, 0, stream>>>(sums, counts, fc1_w, fc1_b, fc2_w, fc2_b, out);
}